// Round 7
// baseline (319.869 us; speedup 1.0000x reference)
//
#include <hip/hip_runtime.h>

#pragma clang fp contract(off)

#define IMG_H 512
#define IMG_W 512
#define TILE_W 64
#define TILE_H 32
#define PAD 2
#define LROWS 36                 // TILE_H + 2*PAD
#define LCOLS 70                 // padded float2 width (2 + 64 + 2 = 68, pad to 70)
#define NTHREADS 256

__device__ __forceinline__ int reflect_idx(int i) {
    // jnp.pad 'reflect': -1 -> 1, 512 -> 510
    i = (i < 0) ? -i : i;
    i = (i >= IMG_H) ? (2 * IMG_H - 2 - i) : i;
    return i;
}

__device__ __forceinline__ float2 gray2(float a0, float a1, float a2,
                                        float b0, float b1, float b2) {
    // bit-identical T_a gray conversion (verified absmax=0.0)
    float2 g;
    g.x = (0.144f * a0 + 0.587f * a1) + 0.299f * a2;
    g.y = (0.144f * b0 + 0.587f * b1) + 0.299f * b2;
    return g;
}

// One interior staging item: 4 adjacent pixels x {3ch img1, 3ch img2}.
// Only 6 float4 loads in flight at a time -> ~24 data VGPRs (vs R5's 48),
// so the kernel fits the 64-VGPR cap and occupancy doubles to 8 waves/SIMD.
// The 3 sequential latency exposures are hidden by the doubled TLP.
__device__ __forceinline__ void stage_quad(float2 (*buf)[LCOLS],
        const float* __restrict__ i1, const float* __restrict__ i2,
        int x0, int y0, int item) {
    const size_t plane = (size_t)IMG_H * IMG_W;
    int r = item >> 4, q = item & 15;
    int gy = reflect_idx(y0 + r - PAD);
    const float* pa = i1 + (size_t)gy * IMG_W + (x0 + 4 * q);
    const float* pb = i2 + (size_t)gy * IMG_W + (x0 + 4 * q);
    float4 A0 = *(const float4*)(pa);
    float4 A1 = *(const float4*)(pa + plane);
    float4 A2 = *(const float4*)(pa + 2 * plane);
    float4 B0 = *(const float4*)(pb);
    float4 B1 = *(const float4*)(pb + plane);
    float4 B2 = *(const float4*)(pb + 2 * plane);
    float2 g0 = gray2(A0.x, A1.x, A2.x, B0.x, B1.x, B2.x);
    float2 g1 = gray2(A0.y, A1.y, A2.y, B0.y, B1.y, B2.y);
    float2 g2 = gray2(A0.z, A1.z, A2.z, B0.z, B1.z, B2.z);
    float2 g3 = gray2(A0.w, A1.w, A2.w, B0.w, B1.w, B2.w);
    float4* dst = (float4*)&buf[r][2 + 4 * q];   // 16B-aligned
    dst[0] = make_float4(g0.x, g0.y, g1.x, g1.y);
    dst[1] = make_float4(g2.x, g2.y, g3.x, g3.y);
}

// T_a chains (verified absmax=0.0): rows ascend, dx ascends within row,
// acc starts 0.0f, mean via s*0.04f recip-mul. Identical to R5.
// __launch_bounds__(256, 8): 8 waves/EU -> 32 waves/CU (8 blocks); caps
// VGPR at 64. LDS 20,160 B x 8 = 161,280 <= 160 KiB -> LDS fits 8 blocks.
__global__ __launch_bounds__(NTHREADS, 8) void texdiff_kernel(
        const float* __restrict__ img1,
        const float* __restrict__ img2,
        float* __restrict__ out) {
    __shared__ float2 g12[LROWS][LCOLS];   // 36*70*8 = 20,160 B

    const int b  = blockIdx.z;
    const int x0 = blockIdx.x * TILE_W;
    const int y0 = blockIdx.y * TILE_H;
    const int tid = threadIdx.x;

    const size_t plane = (size_t)IMG_H * IMG_W;
    const float* i1 = img1 + (size_t)b * 3 * plane;
    const float* i2 = img2 + (size_t)b * 3 * plane;

    // ---- stage: 36 rows x 16 quads = 576 items ----
    stage_quad(g12, i1, i2, x0, y0, tid);
    stage_quad(g12, i1, i2, x0, y0, tid + NTHREADS);
    if (tid < 64) stage_quad(g12, i1, i2, x0, y0, tid + 2 * NTHREADS);
    if (tid < 144) {   // halo: 36 rows x cols {0,1,66,67}
        int r = tid >> 2, s = tid & 3;
        int c = (s < 2) ? s : (s + 64);
        int gy = reflect_idx(y0 + r - PAD);
        int gx = reflect_idx(x0 + c - PAD);
        size_t off = (size_t)gy * IMG_W + gx;
        g12[r][c] = gray2(i1[off], i1[off + plane], i1[off + 2 * plane],
                          i2[off], i2[off + plane], i2[off + 2 * plane]);
    }
    __syncthreads();

    const int cx = tid & 31;       // col-pair: cols 2cx, 2cx+1
    const int ry = tid >> 5;       // 0..7 -> rows ry*4 .. ry*4+3
    const int r0 = ry * 4;
    const int cb = 2 * cx;

    float s1[4][2], q1[4][2], s2[4][2], q2[4][2];
    #pragma unroll
    for (int k = 0; k < 4; ++k) {
        #pragma unroll
        for (int j = 0; j < 2; ++j) {
            s1[k][j] = 0.0f; q1[k][j] = 0.0f;
            s2[k][j] = 0.0f; q2[k][j] = 0.0f;
        }
    }

    // 8 LDS rows serve 4 overlapping windows; each row read ONCE (3x b128).
    #pragma unroll
    for (int rr = 0; rr < 8; ++rr) {
        const float4* vp = (const float4*)&g12[r0 + rr][cb];  // 16B-aligned
        float4 w0 = vp[0], w1 = vp[1], w2 = vp[2];
        float vx[6], vy[6];
        vx[0] = w0.x; vy[0] = w0.y; vx[1] = w0.z; vy[1] = w0.w;
        vx[2] = w1.x; vy[2] = w1.y; vx[3] = w1.z; vy[3] = w1.w;
        vx[4] = w2.x; vy[4] = w2.y; vx[5] = w2.z; vy[5] = w2.w;

        #pragma unroll
        for (int k = 0; k < 4; ++k) {
            if (rr >= k && rr <= k + 4) {   // compile-time predicate
                #pragma unroll
                for (int j = 0; j < 2; ++j) {
                    #pragma unroll
                    for (int dx = 0; dx < 5; ++dx) {
                        float a = vx[dx + j];
                        float c = vy[dx + j];
                        s1[k][j] = s1[k][j] + a;  q1[k][j] = q1[k][j] + a * a;
                        s2[k][j] = s2[k][j] + c;  q2[k][j] = q2[k][j] + c * c;
                    }
                }
            }
        }
    }

    #pragma unroll
    for (int k = 0; k < 4; ++k) {
        float2 o;
        #pragma unroll
        for (int j = 0; j < 2; ++j) {
            float m1 = s1[k][j] * 0.04f;
            float e1 = q1[k][j] * 0.04f;
            float m2 = s2[k][j] * 0.04f;
            float e2 = q2[k][j] * 0.04f;
            float var1 = fmaxf(e1 - m1 * m1, 0.0f);
            float sd1 = sqrtf(var1 + 1e-9f);
            float var2 = fmaxf(e2 - m2 * m2, 0.0f);
            float sd2 = sqrtf(var2 + 1e-9f);
            float num = (2.0f * sd1) * sd2;
            float den = ((sd1 * sd1 + sd2 * sd2) + 1e-5f) + 1e-8f;
            float val = (num / den > 0.975f) ? 1.0f : 0.0f;
            (j == 0 ? o.x : o.y) = val;
        }
        size_t oidx = ((size_t)b * IMG_H + (y0 + r0 + k)) * IMG_W + (x0 + cb);
        *reinterpret_cast<float2*>(&out[oidx]) = o;
    }
}

extern "C" void kernel_launch(void* const* d_in, const int* in_sizes, int n_in,
                              void* d_out, int out_size, void* d_ws, size_t ws_size,
                              hipStream_t stream) {
    const float* img1 = (const float*)d_in[0];
    const float* img2 = (const float*)d_in[1];
    float* out = (float*)d_out;
    dim3 grid(IMG_W / TILE_W, IMG_H / TILE_H, 16);   // 8 x 16 x 16 = 2048 blocks
    texdiff_kernel<<<grid, dim3(NTHREADS), 0, stream>>>(img1, img2, out);
}

// Round 8
// 137.086 us; speedup vs baseline: 2.3333x; 2.3333x over previous
//
#include <hip/hip_runtime.h>

#pragma clang fp contract(off)

#define IMG_H 512
#define IMG_W 512
#define SW 64                    // strip width
#define PAD 2
#define LCOLS 70                 // padded float2 width (2 + 64 + 2 = 68, pad to 70)
#define NTHREADS 256

__device__ __forceinline__ int reflect_idx(int i) {
    // jnp.pad 'reflect': -1 -> 1, 512 -> 510
    i = (i < 0) ? -i : i;
    i = (i >= IMG_H) ? (2 * IMG_H - 2 - i) : i;
    return i;
}

__device__ __forceinline__ float2 gray2(float a0, float a1, float a2,
                                        float b0, float b1, float b2) {
    // bit-identical T_a gray conversion (verified absmax=0.0)
    float2 g;
    g.x = (0.144f * a0 + 0.587f * a1) + 0.299f * a2;
    g.y = (0.144f * b0 + 0.587f * b1) + 0.299f * b2;
    return g;
}

// ---- prologue staging: rows 0..35 of the buffer (gy = Y0-2+r). ----
// Verbatim R5 structure (compiled to 84 VGPR, no spill, verified absmax=0.0).
__device__ __forceinline__ void stage_tile(float2 (*buf)[LCOLS],
        const float* __restrict__ i1, const float* __restrict__ i2,
        int x0, int y0, int tid) {
    const size_t plane = (size_t)IMG_H * IMG_W;

    int it0 = tid;                 // rows 0..15
    int it1 = tid + NTHREADS;      // rows 16..31
    int r0 = it0 >> 4, q0 = it0 & 15;
    int r1 = it1 >> 4, q1 = it1 & 15;
    int gy0 = reflect_idx(y0 + r0 - PAD);
    int gy1 = reflect_idx(y0 + r1 - PAD);
    const float* pa0 = i1 + (size_t)gy0 * IMG_W + (x0 + 4 * q0);
    const float* pb0 = i2 + (size_t)gy0 * IMG_W + (x0 + 4 * q0);
    const float* pa1 = i1 + (size_t)gy1 * IMG_W + (x0 + 4 * q1);
    const float* pb1 = i2 + (size_t)gy1 * IMG_W + (x0 + 4 * q1);

    float4 A0 = *(const float4*)(pa0);
    float4 A1 = *(const float4*)(pa0 + plane);
    float4 A2 = *(const float4*)(pa0 + 2 * plane);
    float4 B0 = *(const float4*)(pb0);
    float4 B1 = *(const float4*)(pb0 + plane);
    float4 B2 = *(const float4*)(pb0 + 2 * plane);
    float4 C0 = *(const float4*)(pa1);
    float4 C1 = *(const float4*)(pa1 + plane);
    float4 C2 = *(const float4*)(pa1 + 2 * plane);
    float4 D0 = *(const float4*)(pb1);
    float4 D1 = *(const float4*)(pb1 + plane);
    float4 D2 = *(const float4*)(pb1 + 2 * plane);

    {
        float2 g0 = gray2(A0.x, A1.x, A2.x, B0.x, B1.x, B2.x);
        float2 g1 = gray2(A0.y, A1.y, A2.y, B0.y, B1.y, B2.y);
        float2 g2 = gray2(A0.z, A1.z, A2.z, B0.z, B1.z, B2.z);
        float2 g3 = gray2(A0.w, A1.w, A2.w, B0.w, B1.w, B2.w);
        float4* dst = (float4*)&buf[r0][2 + 4 * q0];   // 16B-aligned
        dst[0] = make_float4(g0.x, g0.y, g1.x, g1.y);
        dst[1] = make_float4(g2.x, g2.y, g3.x, g3.y);
    }
    {
        float2 g0 = gray2(C0.x, C1.x, C2.x, D0.x, D1.x, D2.x);
        float2 g1 = gray2(C0.y, C1.y, C2.y, D0.y, D1.y, D2.y);
        float2 g2 = gray2(C0.z, C1.z, C2.z, D0.z, D1.z, D2.z);
        float2 g3 = gray2(C0.w, C1.w, C2.w, D0.w, D1.w, D2.w);
        float4* dst = (float4*)&buf[r1][2 + 4 * q1];
        dst[0] = make_float4(g0.x, g0.y, g1.x, g1.y);
        dst[1] = make_float4(g2.x, g2.y, g3.x, g3.y);
    }

    if (tid < 64) {   // tail: rows 32..35
        int it2 = tid + 2 * NTHREADS;
        int r2 = it2 >> 4, q2 = it2 & 15;
        int gy2 = reflect_idx(y0 + r2 - PAD);
        const float* pa2 = i1 + (size_t)gy2 * IMG_W + (x0 + 4 * q2);
        const float* pb2 = i2 + (size_t)gy2 * IMG_W + (x0 + 4 * q2);
        float4 E0 = *(const float4*)(pa2);
        float4 E1 = *(const float4*)(pa2 + plane);
        float4 E2 = *(const float4*)(pa2 + 2 * plane);
        float4 F0 = *(const float4*)(pb2);
        float4 F1 = *(const float4*)(pb2 + plane);
        float4 F2 = *(const float4*)(pb2 + 2 * plane);
        float2 g0 = gray2(E0.x, E1.x, E2.x, F0.x, F1.x, F2.x);
        float2 g1 = gray2(E0.y, E1.y, E2.y, F0.y, F1.y, F2.y);
        float2 g2 = gray2(E0.z, E1.z, E2.z, F0.z, F1.z, F2.z);
        float2 g3 = gray2(E0.w, E1.w, E2.w, F0.w, F1.w, F2.w);
        float4* dst = (float4*)&buf[r2][2 + 4 * q2];
        dst[0] = make_float4(g0.x, g0.y, g1.x, g1.y);
        dst[1] = make_float4(g2.x, g2.y, g3.x, g3.y);
    }

    if (tid < 144) {   // halo: 36 rows x cols {0,1,66,67}
        int r = tid >> 2, s = tid & 3;
        int c = (s < 2) ? s : (s + 64);
        int gy = reflect_idx(y0 + r - PAD);
        int gx = reflect_idx(x0 + c - PAD);
        size_t off = (size_t)gy * IMG_W + gx;
        buf[r][c] = gray2(i1[off], i1[off + plane], i1[off + 2 * plane],
                          i2[off], i2[off + plane], i2[off + 2 * plane]);
    }
}

// T_a chains (verified absmax=0.0): rows ascend, dx ascends within row,
// acc starts 0.0f, mean via s*0.04f recip-mul. Byte-identical fold/epilogue.
#define FOLD_AND_STORE(BASE, YB)                                             \
    {                                                                        \
        float s1[4][2], q1[4][2], s2[4][2], q2[4][2];                        \
        _Pragma("unroll")                                                    \
        for (int k = 0; k < 4; ++k) {                                        \
            _Pragma("unroll")                                                \
            for (int j = 0; j < 2; ++j) {                                    \
                s1[k][j] = 0.0f; q1[k][j] = 0.0f;                            \
                s2[k][j] = 0.0f; q2[k][j] = 0.0f;                            \
            }                                                                \
        }                                                                    \
        _Pragma("unroll")                                                    \
        for (int rr = 0; rr < 8; ++rr) {                                     \
            const float4* vp = (const float4*)&g12[(BASE) + r0c + rr][cb];   \
            float4 w0 = vp[0], w1 = vp[1], w2 = vp[2];                       \
            float vx[6], vy[6];                                              \
            vx[0] = w0.x; vy[0] = w0.y; vx[1] = w0.z; vy[1] = w0.w;          \
            vx[2] = w1.x; vy[2] = w1.y; vx[3] = w1.z; vy[3] = w1.w;          \
            vx[4] = w2.x; vy[4] = w2.y; vx[5] = w2.z; vy[5] = w2.w;          \
            _Pragma("unroll")                                                \
            for (int k = 0; k < 4; ++k) {                                    \
                if (rr >= k && rr <= k + 4) {                                \
                    _Pragma("unroll")                                        \
                    for (int j = 0; j < 2; ++j) {                            \
                        _Pragma("unroll")                                    \
                        for (int dx = 0; dx < 5; ++dx) {                     \
                            float a = vx[dx + j];                            \
                            float c = vy[dx + j];                            \
                            s1[k][j] = s1[k][j] + a;                         \
                            q1[k][j] = q1[k][j] + a * a;                     \
                            s2[k][j] = s2[k][j] + c;                         \
                            q2[k][j] = q2[k][j] + c * c;                     \
                        }                                                    \
                    }                                                        \
                }                                                            \
            }                                                                \
        }                                                                    \
        _Pragma("unroll")                                                    \
        for (int k = 0; k < 4; ++k) {                                        \
            float2 o;                                                        \
            _Pragma("unroll")                                                \
            for (int j = 0; j < 2; ++j) {                                    \
                float m1 = s1[k][j] * 0.04f;                                 \
                float e1 = q1[k][j] * 0.04f;                                 \
                float m2 = s2[k][j] * 0.04f;                                 \
                float e2 = q2[k][j] * 0.04f;                                 \
                float var1 = fmaxf(e1 - m1 * m1, 0.0f);                      \
                float sd1 = sqrtf(var1 + 1e-9f);                             \
                float var2 = fmaxf(e2 - m2 * m2, 0.0f);                      \
                float sd2 = sqrtf(var2 + 1e-9f);                             \
                float num = (2.0f * sd1) * sd2;                              \
                float den = ((sd1 * sd1 + sd2 * sd2) + 1e-5f) + 1e-8f;       \
                float val = (num / den > 0.975f) ? 1.0f : 0.0f;              \
                (j == 0 ? o.x : o.y) = val;                                  \
            }                                                                \
            size_t oidx = ((size_t)b * IMG_H + ((YB) + r0c + k)) * IMG_W     \
                          + (x0 + cb);                                       \
            *reinterpret_cast<float2*>(&out[oidx]) = o;                      \
        }                                                                    \
    }

// Block = 64x64 strip, 2 chunks of 32 rows, one 68-row LDS buffer.
// Pipeline: stage rows 0..35; sync; ISSUE chunk-1 raw loads (rows 36..67,
// no use); fold chunk 0 (~2200 cyc, loads in flight); gray+ds_write chunk 1
// (the only vmcnt wait -- satisfied long ago); sync; fold chunk 1.
// Fold-0 reads LDS rows 0..35; chunk-1 writes rows 36..67 -> disjoint, so
// early-finishing threads racing ahead cannot clobber rows being read.
__global__ __launch_bounds__(NTHREADS) void texdiff_kernel(
        const float* __restrict__ img1,
        const float* __restrict__ img2,
        float* __restrict__ out) {
    __shared__ float2 g12[68][LCOLS];   // 68*70*8 = 38,080 B

    const int b  = blockIdx.z;
    const int x0 = blockIdx.x * SW;
    const int Y0 = blockIdx.y * 64;     // strip rows Y0..Y0+63
    const int tid = threadIdx.x;

    const size_t plane = (size_t)IMG_H * IMG_W;
    const float* i1 = img1 + (size_t)b * 3 * plane;
    const float* i2 = img2 + (size_t)b * 3 * plane;

    // ---- prologue: buffer rows 0..35 (gy = Y0-2 .. Y0+33) ----
    stage_tile(g12, i1, i2, x0, Y0, tid);
    __syncthreads();

    // ---- issue chunk-1 raw loads: buffer rows 36..67 (gy = Y0+34..Y0+65) ----
    const int ra = tid >> 4;            // 0..15
    const int qa = tid & 15;
    const int rb = ra + 16;             // 16..31
    const int gya = reflect_idx(Y0 + 34 + ra);
    const int gyb = reflect_idx(Y0 + 34 + rb);
    const float* paa = i1 + (size_t)gya * IMG_W + (x0 + 4 * qa);
    const float* pba = i2 + (size_t)gya * IMG_W + (x0 + 4 * qa);
    const float* pab = i1 + (size_t)gyb * IMG_W + (x0 + 4 * qa);
    const float* pbb = i2 + (size_t)gyb * IMG_W + (x0 + 4 * qa);
    float4 A0 = *(const float4*)(paa);
    float4 A1 = *(const float4*)(paa + plane);
    float4 A2 = *(const float4*)(paa + 2 * plane);
    float4 B0 = *(const float4*)(pba);
    float4 B1 = *(const float4*)(pba + plane);
    float4 B2 = *(const float4*)(pba + 2 * plane);
    float4 C0 = *(const float4*)(pab);
    float4 C1 = *(const float4*)(pab + plane);
    float4 C2 = *(const float4*)(pab + 2 * plane);
    float4 D0 = *(const float4*)(pbb);
    float4 D1 = *(const float4*)(pbb + plane);
    float4 D2 = *(const float4*)(pbb + 2 * plane);

    float h0 = 0, h1 = 0, h2 = 0, h3 = 0, h4 = 0, h5 = 0;
    int hr = 0, hc = 0;
    if (tid < 128) {   // chunk-1 halo: 32 rows x cols {0,1,66,67}
        hr = tid >> 2;
        int s = tid & 3;
        hc = (s < 2) ? s : (s + 64);
        int gy = reflect_idx(Y0 + 34 + hr);
        int gx = reflect_idx(x0 + hc - PAD);
        size_t off = (size_t)gy * IMG_W + gx;
        h0 = i1[off]; h1 = i1[off + plane]; h2 = i1[off + 2 * plane];
        h3 = i2[off]; h4 = i2[off + plane]; h5 = i2[off + 2 * plane];
    }

    const int cx = tid & 31;       // col-pair: cols 2cx, 2cx+1
    const int ry = tid >> 5;       // 0..7 -> rows ry*4 .. ry*4+3
    const int r0c = ry * 4;
    const int cb = 2 * cx;

    // ---- fold chunk 0 (loads above stay in flight under ~2200 cyc VALU) ----
    FOLD_AND_STORE(0, Y0)

    // ---- gray + write chunk 1 (vmcnt wait lands here, already satisfied) ----
    {
        float2 g0 = gray2(A0.x, A1.x, A2.x, B0.x, B1.x, B2.x);
        float2 g1 = gray2(A0.y, A1.y, A2.y, B0.y, B1.y, B2.y);
        float2 g2 = gray2(A0.z, A1.z, A2.z, B0.z, B1.z, B2.z);
        float2 g3 = gray2(A0.w, A1.w, A2.w, B0.w, B1.w, B2.w);
        float4* dst = (float4*)&g12[36 + ra][2 + 4 * qa];
        dst[0] = make_float4(g0.x, g0.y, g1.x, g1.y);
        dst[1] = make_float4(g2.x, g2.y, g3.x, g3.y);
    }
    {
        float2 g0 = gray2(C0.x, C1.x, C2.x, D0.x, D1.x, D2.x);
        float2 g1 = gray2(C0.y, C1.y, C2.y, D0.y, D1.y, D2.y);
        float2 g2 = gray2(C0.z, C1.z, C2.z, D0.z, D1.z, D2.z);
        float2 g3 = gray2(C0.w, C1.w, C2.w, D0.w, D1.w, D2.w);
        float4* dst = (float4*)&g12[36 + rb][2 + 4 * qa];
        dst[0] = make_float4(g0.x, g0.y, g1.x, g1.y);
        dst[1] = make_float4(g2.x, g2.y, g3.x, g3.y);
    }
    if (tid < 128) g12[36 + hr][hc] = gray2(h0, h1, h2, h3, h4, h5);
    __syncthreads();

    // ---- fold chunk 1 ----
    FOLD_AND_STORE(32, Y0 + 32)
}

extern "C" void kernel_launch(void* const* d_in, const int* in_sizes, int n_in,
                              void* d_out, int out_size, void* d_ws, size_t ws_size,
                              hipStream_t stream) {
    const float* img1 = (const float*)d_in[0];
    const float* img2 = (const float*)d_in[1];
    float* out = (float*)d_out;
    dim3 grid(IMG_W / SW, IMG_H / 64, 16);   // 8 x 8 x 16 = 1024 blocks
    texdiff_kernel<<<grid, dim3(NTHREADS), 0, stream>>>(img1, img2, out);
}

// Round 9
// 136.919 us; speedup vs baseline: 2.3362x; 1.0012x over previous
//
#include <hip/hip_runtime.h>

#pragma clang fp contract(off)

#define IMG_H 512
#define IMG_W 512
#define TILE_W 64
#define TILE_H 32
#define PAD 2
#define LROWS 36                 // TILE_H + 2*PAD
#define LCOLS 68                 // 2 + 64 + 2 halo-first layout, NO extra pad
#define NTHREADS 256

__device__ __forceinline__ int reflect_idx(int i) {
    // jnp.pad 'reflect': -1 -> 1, 512 -> 510
    i = (i < 0) ? -i : i;
    i = (i >= IMG_H) ? (2 * IMG_H - 2 - i) : i;
    return i;
}

__device__ __forceinline__ float2 gray2(float a0, float a1, float a2,
                                        float b0, float b1, float b2) {
    // bit-identical T_a gray conversion (verified absmax=0.0)
    float2 g;
    g.x = (0.144f * a0 + 0.587f * a1) + 0.299f * a2;
    g.y = (0.144f * b0 + 0.587f * b1) + 0.299f * b2;
    return g;
}

__device__ __forceinline__ float4 gray4(float4 c0, float4 c1, float4 c2) {
    // same op per lane as gray2 (identical rounding)
    float4 g;
    g.x = (0.144f * c0.x + 0.587f * c1.x) + 0.299f * c2.x;
    g.y = (0.144f * c0.y + 0.587f * c1.y) + 0.299f * c2.y;
    g.z = (0.144f * c0.z + 0.587f * c1.z) + 0.299f * c2.z;
    g.w = (0.144f * c0.w + 0.587f * c1.w) + 0.299f * c2.w;
    return g;
}

// One staging item = 4 adjacent pixels. VGPR-lean: img1's 3 planes are
// loaded and fully consumed into 4 grays BEFORE img2's planes load, so
// only ~12 data regs are in flight at once (vs 24/48 in R5/R8). The
// sched_barrier(0) calls in the caller stop the compiler from re-merging
// quads into one big batch (that's what pushed R8 to 128 VGPR).
__device__ __forceinline__ void stage_quad(float2 (*buf)[LCOLS],
        const float* __restrict__ i1, const float* __restrict__ i2,
        int x0, int y0, int item) {
    const size_t plane = (size_t)IMG_H * IMG_W;
    int r = item >> 4, q = item & 15;
    int gy = reflect_idx(y0 + r - PAD);
    const float* pa = i1 + (size_t)gy * IMG_W + (x0 + 4 * q);
    float4 A0 = *(const float4*)(pa);
    float4 A1 = *(const float4*)(pa + plane);
    float4 A2 = *(const float4*)(pa + 2 * plane);
    float4 ga = gray4(A0, A1, A2);
    const float* pb = i2 + (size_t)gy * IMG_W + (x0 + 4 * q);
    float4 B0 = *(const float4*)(pb);
    float4 B1 = *(const float4*)(pb + plane);
    float4 B2 = *(const float4*)(pb + 2 * plane);
    float4 gb = gray4(B0, B1, B2);
    float2* d = &buf[r][2 + 4 * q];   // 8B-aligned (LCOLS=68)
    d[0] = make_float2(ga.x, gb.x);
    d[1] = make_float2(ga.y, gb.y);
    d[2] = make_float2(ga.z, gb.z);
    d[3] = make_float2(ga.w, gb.w);
}

// T_a chains (verified absmax=0.0): rows ascend, dx ascends within row,
// acc starts 0.0f, mean via s*0.04f recip-mul. Fold/epilogue identical to
// R5; only the staging register shape and LCOLS changed (data movement).
// Goal: natural VGPR <= 64 -> 8 waves/SIMD (32/CU, vs R5's 16).
// LDS 19,584 B x 8 blocks = 153 KiB <= 160 KiB.
__global__ __launch_bounds__(NTHREADS) void texdiff_kernel(
        const float* __restrict__ img1,
        const float* __restrict__ img2,
        float* __restrict__ out) {
    __shared__ float2 g12[LROWS][LCOLS];   // 36*68*8 = 19,584 B

    const int b  = blockIdx.z;
    const int x0 = blockIdx.x * TILE_W;
    const int y0 = blockIdx.y * TILE_H;
    const int tid = threadIdx.x;

    const size_t plane = (size_t)IMG_H * IMG_W;
    const float* i1 = img1 + (size_t)b * 3 * plane;
    const float* i2 = img2 + (size_t)b * 3 * plane;

    // ---- stage: 36 rows x 16 quads = 576 items ----
    stage_quad(g12, i1, i2, x0, y0, tid);
    __builtin_amdgcn_sched_barrier(0);
    stage_quad(g12, i1, i2, x0, y0, tid + NTHREADS);
    __builtin_amdgcn_sched_barrier(0);
    if (tid < 64) stage_quad(g12, i1, i2, x0, y0, tid + 2 * NTHREADS);
    __builtin_amdgcn_sched_barrier(0);
    if (tid < 144) {   // halo: 36 rows x cols {0,1,66,67}
        int r = tid >> 2, s = tid & 3;
        int c = (s < 2) ? s : (s + 64);
        int gy = reflect_idx(y0 + r - PAD);
        int gx = reflect_idx(x0 + c - PAD);
        size_t off = (size_t)gy * IMG_W + gx;
        g12[r][c] = gray2(i1[off], i1[off + plane], i1[off + 2 * plane],
                          i2[off], i2[off + plane], i2[off + 2 * plane]);
    }
    __syncthreads();

    const int cx = tid & 31;       // col-pair: cols 2cx, 2cx+1
    const int ry = tid >> 5;       // 0..7 -> rows ry*4 .. ry*4+3
    const int r0 = ry * 4;
    const int cb = 2 * cx;

    float s1[4][2], q1[4][2], s2[4][2], q2[4][2];
    #pragma unroll
    for (int k = 0; k < 4; ++k) {
        #pragma unroll
        for (int j = 0; j < 2; ++j) {
            s1[k][j] = 0.0f; q1[k][j] = 0.0f;
            s2[k][j] = 0.0f; q2[k][j] = 0.0f;
        }
    }

    // 8 LDS rows serve 4 overlapping windows; each row read ONCE (3x b128,
    // 16B-aligned: 272*r + 16*cx).
    #pragma unroll
    for (int rr = 0; rr < 8; ++rr) {
        const float4* vp = (const float4*)&g12[r0 + rr][cb];
        float4 w0 = vp[0], w1 = vp[1], w2 = vp[2];
        float vx[6], vy[6];
        vx[0] = w0.x; vy[0] = w0.y; vx[1] = w0.z; vy[1] = w0.w;
        vx[2] = w1.x; vy[2] = w1.y; vx[3] = w1.z; vy[3] = w1.w;
        vx[4] = w2.x; vy[4] = w2.y; vx[5] = w2.z; vy[5] = w2.w;

        #pragma unroll
        for (int k = 0; k < 4; ++k) {
            if (rr >= k && rr <= k + 4) {   // compile-time predicate
                #pragma unroll
                for (int j = 0; j < 2; ++j) {
                    #pragma unroll
                    for (int dx = 0; dx < 5; ++dx) {
                        float a = vx[dx + j];
                        float c = vy[dx + j];
                        s1[k][j] = s1[k][j] + a;  q1[k][j] = q1[k][j] + a * a;
                        s2[k][j] = s2[k][j] + c;  q2[k][j] = q2[k][j] + c * c;
                    }
                }
            }
        }
    }

    #pragma unroll
    for (int k = 0; k < 4; ++k) {
        float2 o;
        #pragma unroll
        for (int j = 0; j < 2; ++j) {
            float m1 = s1[k][j] * 0.04f;
            float e1 = q1[k][j] * 0.04f;
            float m2 = s2[k][j] * 0.04f;
            float e2 = q2[k][j] * 0.04f;
            float var1 = fmaxf(e1 - m1 * m1, 0.0f);
            float sd1 = sqrtf(var1 + 1e-9f);
            float var2 = fmaxf(e2 - m2 * m2, 0.0f);
            float sd2 = sqrtf(var2 + 1e-9f);
            float num = (2.0f * sd1) * sd2;
            float den = ((sd1 * sd1 + sd2 * sd2) + 1e-5f) + 1e-8f;
            float val = (num / den > 0.975f) ? 1.0f : 0.0f;
            (j == 0 ? o.x : o.y) = val;
        }
        size_t oidx = ((size_t)b * IMG_H + (y0 + r0 + k)) * IMG_W + (x0 + cb);
        *reinterpret_cast<float2*>(&out[oidx]) = o;
    }
}

extern "C" void kernel_launch(void* const* d_in, const int* in_sizes, int n_in,
                              void* d_out, int out_size, void* d_ws, size_t ws_size,
                              hipStream_t stream) {
    const float* img1 = (const float*)d_in[0];
    const float* img2 = (const float*)d_in[1];
    float* out = (float*)d_out;
    dim3 grid(IMG_W / TILE_W, IMG_H / TILE_H, 16);   // 8 x 16 x 16 = 2048 blocks
    texdiff_kernel<<<grid, dim3(NTHREADS), 0, stream>>>(img1, img2, out);
}